// Round 2
// baseline (556.502 us; speedup 1.0000x reference)
//
#include <hip/hip_runtime.h>

#define BB 256
#define TT 2048
#define II 128
#define HH 128
#define GS 16              // steps per group
#define NG (TT / GS)       // 128 groups

typedef __attribute__((ext_vector_type(8))) short short8;  // 8 bf16 (4 VGPR)
typedef __attribute__((ext_vector_type(4))) float f32x4;   // MFMA C/D

// Light per-step barrier: drain LDS ops then barrier in ONE asm block
// (vmcnt NOT drained — x-prefetch loads / out-stores fly across steps).
__device__ __forceinline__ void step_barrier() {
    asm volatile("s_waitcnt lgkmcnt(0)\n\ts_barrier" ::: "memory");
}

__device__ __forceinline__ float tanh_fast(float s) {
    // tanh(s) = 1 - 2/(e^{2s}+1); e^{2s} = 2^(s * 2/ln2), one v_exp_f32.
    // Saturates correctly: s>>0 -> exp2=inf -> rcp=0 -> 1; s<<0 -> -1.
#if __has_builtin(__builtin_amdgcn_exp2f)
    const float e = __builtin_amdgcn_exp2f(s * 2.8853900817779268f);
#else
    const float e = exp2f(s * 2.8853900817779268f);
#endif
    return 1.0f - 2.0f * __builtin_amdgcn_rcpf(e + 1.0f);
}

// float -> bf16 round-to-nearest-even
__device__ __forceinline__ unsigned int f2bf(float f) {
    unsigned int u = __float_as_uint(f);
    u += 0x7FFF + ((u >> 16) & 1);
    return u >> 16;
}
__device__ __forceinline__ unsigned int pack2(float lo, float hi) {
    return f2bf(lo) | (f2bf(hi) << 16);
}

// R15: merge x-waves into h-waves -> 4 SYMMETRIC waves (256 thr), 1/SIMD.
// R14 measured 608 cyc/step; MFMA budget is only 130 c/SIMD IF balanced.
// With 8 waves (4h+4x) on 4 SIMDs the wave->SIMD pairing is uncontrolled:
// two h-waves on one SIMD serialize 16 MFMAs (258 c) while another SIMD
// idles, and the per-step barrier syncs 8 role-asymmetric waves. Now every
// wave owns 32 cols for BOTH the h-matvec (identical 8-MFMA step) and the
// x-projection (folded into step w==0, +2 amortized MFMAs/step):
// guaranteed SIMD balance, barrier width 8->4, lockstep arrival.
// h-step datapath is R14 verbatim (broadcast A, 8 indep accs, permuted hA
// k-layout + single ds_write_b32, ax register prefetch, fire-and-forget
// out stores). Arithmetic bit-identical -> absmax unchanged.
__launch_bounds__(256, 1)
__global__ void rnn_pipe(const float* __restrict__ x,
                         const float* __restrict__ w_ih,
                         const float* __restrict__ w_hh,
                         const float* __restrict__ b_ih,
                         const float* __restrict__ b_hh,
                         float* __restrict__ out) {
    const int b    = blockIdx.x;
    const int tid  = threadIdx.x;
    const int wave = tid >> 6;
    const int lane = tid & 63;
    const int jb   = wave * 32;      // this wave owns cols [jb, jb+32)

    __shared__ __align__(16) unsigned short hA[2][HH];           // bf16 h ping-pong (k-permuted)
    __shared__ __align__(16) float axbuf[2][GS][HH];             // 16 KB
    __shared__ __align__(16) unsigned short xstage[2][4][64][8]; // 8 KB bf16 A-frags

    const float* xb = x + (size_t)b * (TT * II);

    // ---------------- W_hh B-frags (bf16, k-permuted) ----------------
    short8 WH[2][4];
#pragma unroll
    for (int nt = 0; nt < 2; ++nt) {
        const int jj = jb + nt * 16 + (lane & 15);
#pragma unroll
        for (int kf = 0; kf < 4; ++kf) {
            short8 s;
#pragma unroll
            for (int e = 0; e < 8; ++e) {
                const int kp = kf * 32 + (lane >> 4) * 8 + e;  // A-slot index
                const int mm = kp & 31;
                // slot -> original k: 32a+2c -> 32a+c ; 32a+2c+1 -> 32a+16+c
                const int ko = (kp & ~31) + (mm >> 1) + ((mm & 1) << 4);
                s[e] = (short)f2bf(w_hh[(size_t)jj * HH + ko]);
            }
            WH[nt][kf] = s;
        }
    }

    // ---------------- W_ih B-frags + bias ----------------
    short8 WF[2][4];
    float biasv[2];
#pragma unroll
    for (int nt = 0; nt < 2; ++nt) {
        const int jj = jb + nt * 16 + (lane & 15);
        biasv[nt] = b_ih[jj] + b_hh[jj];
#pragma unroll
        for (int kf = 0; kf < 4; ++kf) {
            const float* wp = w_ih + (size_t)jj * II + kf * 32 + (lane >> 4) * 8;
            short8 s;
#pragma unroll
            for (int e = 0; e < 8; ++e) s[e] = (short)f2bf(wp[e]);
            WF[nt][kf] = s;
        }
    }

    // x-staging thread mapping (256 threads)
    const int t_s = tid >> 4;                // timestep 0..15
    const int m   = tid & 15;
    const int i0  = m * 8;
    const int kfs = m >> 2;                  // k-frag of this chunk
    const int lps = (m & 3) * 16 + t_s;      // A-frag lane slot

#define STAGE_X(BUF, R0, R1) do { \
        uint4 P_; P_.x = pack2((R0).x, (R0).y); P_.y = pack2((R0).z, (R0).w); \
        P_.z = pack2((R1).x, (R1).y); P_.w = pack2((R1).z, (R1).w); \
        *reinterpret_cast<uint4*>(&xstage[BUF][kfs][lps][0]) = P_; } while (0)

#define XPROJ(SB, AB) do { \
        const short8 XA0 = *reinterpret_cast<const short8*>(&xstage[SB][0][lane][0]); \
        const short8 XA1 = *reinterpret_cast<const short8*>(&xstage[SB][1][lane][0]); \
        const short8 XA2 = *reinterpret_cast<const short8*>(&xstage[SB][2][lane][0]); \
        const short8 XA3 = *reinterpret_cast<const short8*>(&xstage[SB][3][lane][0]); \
        f32x4 ac0 = {0.f, 0.f, 0.f, 0.f}, ac1 = {0.f, 0.f, 0.f, 0.f}; \
        ac0 = __builtin_amdgcn_mfma_f32_16x16x32_bf16(XA0, WF[0][0], ac0, 0, 0, 0); \
        ac0 = __builtin_amdgcn_mfma_f32_16x16x32_bf16(XA1, WF[0][1], ac0, 0, 0, 0); \
        ac0 = __builtin_amdgcn_mfma_f32_16x16x32_bf16(XA2, WF[0][2], ac0, 0, 0, 0); \
        ac0 = __builtin_amdgcn_mfma_f32_16x16x32_bf16(XA3, WF[0][3], ac0, 0, 0, 0); \
        ac1 = __builtin_amdgcn_mfma_f32_16x16x32_bf16(XA0, WF[1][0], ac1, 0, 0, 0); \
        ac1 = __builtin_amdgcn_mfma_f32_16x16x32_bf16(XA1, WF[1][1], ac1, 0, 0, 0); \
        ac1 = __builtin_amdgcn_mfma_f32_16x16x32_bf16(XA2, WF[1][2], ac1, 0, 0, 0); \
        ac1 = __builtin_amdgcn_mfma_f32_16x16x32_bf16(XA3, WF[1][3], ac1, 0, 0, 0); \
        const int c_ = lane & 15, rb_ = (lane >> 4) * 4; \
        _Pragma("unroll") \
        for (int r = 0; r < 4; ++r) { \
            axbuf[AB][rb_ + r][jb + c_]      = ac0[r] + biasv[0]; \
            axbuf[AB][rb_ + r][jb + 16 + c_] = ac1[r] + biasv[1]; \
        } } while (0)

    // ---------------- prologue ----------------
    float4 nr0, nr1;
    {
        float4 p0 = *reinterpret_cast<const float4*>(&xb[t_s * II + i0]);
        float4 p1 = *reinterpret_cast<const float4*>(&xb[t_s * II + i0 + 4]);
        STAGE_X(1, p0, p1);
        nr0 = *reinterpret_cast<const float4*>(&xb[(GS + t_s) * II + i0]);
        nr1 = *reinterpret_cast<const float4*>(&xb[(GS + t_s) * II + i0 + 4]);
    }
    if (tid < HH) hA[0][tid] = 0;          // bf16 zero (permutation-invariant)
    __syncthreads();
    XPROJ(1, 0);             // axbuf[0] (group 0) — all 4 waves
    STAGE_X(0, nr0, nr1);    // xstage[0] <- x of group 1
    __syncthreads();

    // ax prefetch registers: ax for the step ABOUT to run
    const int c16 = lane & 15;
    float axn0 = axbuf[0][0][jb + c16];
    float axn1 = axbuf[0][0][jb + 16 + c16];

    // rolling out pointer (lanes<16 store; others just carry it)
    float* ob = out + (size_t)b * (TT * HH) + jb + lane;

    // ---------------- main loop ----------------
    for (int g = 0; g < NG; ++g) {
#pragma unroll
        for (int w = 0; w < GS; ++w) {
            const int p  = w & 1;
            const int ko = (lane >> 4) * 8;
            // A = h broadcast into all 16 rows (permuted k-layout matches WH)
            const short8 A0 = *reinterpret_cast<const short8*>(&hA[p][ 0 + ko]);
            const short8 A1 = *reinterpret_cast<const short8*>(&hA[p][32 + ko]);
            const short8 A2 = *reinterpret_cast<const short8*>(&hA[p][64 + ko]);
            const short8 A3 = *reinterpret_cast<const short8*>(&hA[p][96 + ko]);

            // x-pipeline work, folded into designated steps (overlaps the
            // h ds_read latency window; +2 amortized MFMAs/step)
            if (w == 0 && g + 1 < NG) {
                XPROJ(g & 1, (g + 1) & 1);   // ax for group g+1
            }
            if (w == 1 && g + 2 < NG) {
                const int tb = (g + 2) * GS;
                nr0 = *reinterpret_cast<const float4*>(&xb[(size_t)(tb + t_s) * II + i0]);
                nr1 = *reinterpret_cast<const float4*>(&xb[(size_t)(tb + t_s) * II + i0 + 4]);
            }
            if (w == 8 && g + 2 < NG) {
                STAGE_X((g + 1) & 1, nr0, nr1);   // x of group g+2
            }

            // 8 INDEPENDENT accumulators: no MFMA C-chain on the critical path
            f32x4 a0 = {0.f,0.f,0.f,0.f}, a1 = {0.f,0.f,0.f,0.f};
            f32x4 a2 = {0.f,0.f,0.f,0.f}, a3 = {0.f,0.f,0.f,0.f};
            f32x4 c0 = {0.f,0.f,0.f,0.f}, c1 = {0.f,0.f,0.f,0.f};
            f32x4 c2 = {0.f,0.f,0.f,0.f}, c3 = {0.f,0.f,0.f,0.f};
            a0 = __builtin_amdgcn_mfma_f32_16x16x32_bf16(A0, WH[0][0], a0, 0, 0, 0);
            a1 = __builtin_amdgcn_mfma_f32_16x16x32_bf16(A1, WH[0][1], a1, 0, 0, 0);
            a2 = __builtin_amdgcn_mfma_f32_16x16x32_bf16(A2, WH[0][2], a2, 0, 0, 0);
            a3 = __builtin_amdgcn_mfma_f32_16x16x32_bf16(A3, WH[0][3], a3, 0, 0, 0);
            c0 = __builtin_amdgcn_mfma_f32_16x16x32_bf16(A0, WH[1][0], c0, 0, 0, 0);
            c1 = __builtin_amdgcn_mfma_f32_16x16x32_bf16(A1, WH[1][1], c1, 0, 0, 0);
            c2 = __builtin_amdgcn_mfma_f32_16x16x32_bf16(A2, WH[1][2], c2, 0, 0, 0);
            c3 = __builtin_amdgcn_mfma_f32_16x16x32_bf16(A3, WH[1][3], c3, 0, 0, 0);

            // consume current-step ax, then prefetch next step's (hidden
            // under MFMA completion; buffer is valid a full group ahead)
            const float axv0 = axn0, axv1 = axn1;
            {
                const int wn  = (w + 1) & (GS - 1);
                const int gnb = (w == GS - 1) ? ((g + 1) & 1) : (g & 1);
                axn0 = axbuf[gnb][wn][jb + c16];
                axn1 = axbuf[gnb][wn][jb + 16 + c16];
            }

            // 2-level add tree (every lane holds col (lane&15) redundantly)
            const float s0 = (a0[0] + a1[0]) + (a2[0] + a3[0]) + axv0;
            const float s1 = (c0[0] + c1[0]) + (c2[0] + c3[0]) + axv1;
            const float hn0 = tanh_fast(s0);
            const float hn1 = tanh_fast(s1);
            if (lane < 16) {
                // permuted layout: cols (jb+lane, jb+16+lane) are adjacent
                // slots -> ONE packed dword write
                *reinterpret_cast<unsigned int*>(&hA[p ^ 1][jb + 2 * lane])
                    = pack2(hn0, hn1);
                ob[0]  = hn0;     // fire-and-forget; no vmcnt wait in loop
                ob[16] = hn1;
            }
            ob += HH;
            step_barrier();
        }
    }
#undef XPROJ
#undef STAGE_X
}

extern "C" void kernel_launch(void* const* d_in, const int* in_sizes, int n_in,
                              void* d_out, int out_size, void* d_ws, size_t ws_size,
                              hipStream_t stream) {
    const float* x    = (const float*)d_in[0];
    const float* w_ih = (const float*)d_in[1];
    const float* w_hh = (const float*)d_in[2];
    const float* b_ih = (const float*)d_in[3];
    const float* b_hh = (const float*)d_in[4];
    float* out = (float*)d_out;

    rnn_pipe<<<BB, 256, 0, stream>>>(x, w_ih, w_hh, b_ih, b_hh, out);
}

// Round 3
// 512.552 us; speedup vs baseline: 1.0857x; 1.0857x over previous
//
#include <hip/hip_runtime.h>

#define BB 256
#define TT 2048
#define II 128
#define HH 128
#define GS 16              // steps per group
#define NG (TT / GS)       // 128 groups

typedef __attribute__((ext_vector_type(8))) short short8;  // 8 bf16 (4 VGPR)
typedef __attribute__((ext_vector_type(4))) float f32x4;   // MFMA C/D

// Light per-step barrier: drain LDS ops then barrier in ONE asm block
// (vmcnt NOT drained — x-prefetch loads / out-stores fly across steps).
__device__ __forceinline__ void step_barrier() {
    asm volatile("s_waitcnt lgkmcnt(0)\n\ts_barrier" ::: "memory");
}

__device__ __forceinline__ float tanh_fast(float s) {
    // tanh(s) = 1 - 2/(e^{2s}+1); e^{2s} = 2^(s * 2/ln2), one v_exp_f32.
#if __has_builtin(__builtin_amdgcn_exp2f)
    const float e = __builtin_amdgcn_exp2f(s * 2.8853900817779268f);
#else
    const float e = exp2f(s * 2.8853900817779268f);
#endif
    return 1.0f - 2.0f * __builtin_amdgcn_rcpf(e + 1.0f);
}

// float -> bf16 round-to-nearest-even
__device__ __forceinline__ unsigned int f2bf(float f) {
    unsigned int u = __float_as_uint(f);
    u += 0x7FFF + ((u >> 16) & 1);
    return u >> 16;
}
__device__ __forceinline__ unsigned int pack2(float lo, float hi) {
    return f2bf(lo) | (f2bf(hi) << 16);
}

// R16: revert to R14's proven 8-wave (4h+4x) split (R15's 4-wave merge put
// x-work on the serial chain: +95 c/step). On top of R14:
//  (1) Zero-init elimination: R14 re-zeroed 8 f32x4 accs per step = 32
//      v_mov (VALUBusy 29.7% ~= 180c/SIMD/step). Now a hoisted z4 constant
//      feeds 6 accs as the MFMA C operand directly (no movs), and the 2
//      ax-seeded accs are PERSISTENT regs with one in-place d[0]=ax write
//      (stale [1..3] accumulate unread garbage, bounded ~2e4 — harmless).
//      Also folds the +ax VALU add into the MFMA.
//  (2) XPROJ de-spiked: group-ahead x-projection spread 1 MFMA/step over
//      w=1..8 (C-seeded with hoisted bias splats; no chain), tree+stores
//      at w==9, STAGE at w==11. Removes the w==0 16-MFMA/SIMD barrier
//      spike and the 4-deep MFMA dependency chain.
//  (3) Rolling out pointer.
// h datapath otherwise R14 verbatim: broadcast-A ds_reads, permuted hA
// k-layout + single packed ds_write_b32, ax register prefetch,
// fire-and-forget out stores, light lgkm-only step barrier.
__launch_bounds__(512, 1)
__global__ void rnn_pipe(const float* __restrict__ x,
                         const float* __restrict__ w_ih,
                         const float* __restrict__ w_hh,
                         const float* __restrict__ b_ih,
                         const float* __restrict__ b_hh,
                         float* __restrict__ out) {
    const int b    = blockIdx.x;
    const int tid  = threadIdx.x;
    const int wave = tid >> 6;
    const int lane = tid & 63;
    const bool hw  = (wave < 4);

    __shared__ __align__(16) unsigned short hA[2][HH];           // bf16 h ping-pong (k-permuted)
    __shared__ __align__(16) float axbuf[2][GS][HH];             // 16 KB
    __shared__ __align__(16) unsigned short xstage[2][4][64][8]; // 8 KB bf16 A-frags

    const float* xb = x + (size_t)b * (TT * II);
    const f32x4 z4 = {0.f, 0.f, 0.f, 0.f};   // hoisted MFMA C zero

    // ---------------- h-wave setup: W_hh B-frags (bf16, k-permuted) ----------------
    const int jb_h = (wave & 3) * 32;    // h-wave owns cols [jb_h, jb_h+32)
    short8 WH[2][4];
    if (hw) {
#pragma unroll
        for (int nt = 0; nt < 2; ++nt) {
            const int jj = jb_h + nt * 16 + (lane & 15);
#pragma unroll
            for (int kf = 0; kf < 4; ++kf) {
                short8 s;
#pragma unroll
                for (int e = 0; e < 8; ++e) {
                    const int kp = kf * 32 + (lane >> 4) * 8 + e;  // A-slot index
                    const int mm = kp & 31;
                    // slot -> original k: 32a+2c -> 32a+c ; 32a+2c+1 -> 32a+16+c
                    const int ko = (kp & ~31) + (mm >> 1) + ((mm & 1) << 4);
                    s[e] = (short)f2bf(w_hh[(size_t)jj * HH + ko]);
                }
                WH[nt][kf] = s;
            }
        }
    }

    // ---------------- x-wave setup ----------------
    const int xwq = wave - 4;        // 0..3
    const int jb  = xwq * 32;        // owns j in [jb, jb+32): 2 N-tiles
    short8 WF[2][4];
    float biasv[2];
    f32x4 bs0 = z4, bs1 = z4;        // bias splats (MFMA C seeds)
    const int q   = tid - 256;       // 0..255 for x-threads
    const int t_s = q >> 4;          // 0..15
    const int m   = q & 15;
    const int i0  = m * 8;
    const int kfs = m >> 2;                  // k-frag of this chunk
    const int lps = (m & 3) * 16 + t_s;      // A-frag lane slot
    if (!hw) {
#pragma unroll
        for (int nt = 0; nt < 2; ++nt) {
            const int jj = jb + nt * 16 + (lane & 15);
            biasv[nt] = b_ih[jj] + b_hh[jj];
#pragma unroll
            for (int kf = 0; kf < 4; ++kf) {
                const float* wp = w_ih + (size_t)jj * II + kf * 32 + (lane >> 4) * 8;
                short8 s;
#pragma unroll
                for (int e = 0; e < 8; ++e) s[e] = (short)f2bf(wp[e]);
                WF[nt][kf] = s;
            }
        }
#pragma unroll
        for (int r = 0; r < 4; ++r) { bs0[r] = biasv[0]; bs1[r] = biasv[1]; }
    }

#define STAGE_X(BUF, R0, R1) do { \
        uint4 P_; P_.x = pack2((R0).x, (R0).y); P_.y = pack2((R0).z, (R0).w); \
        P_.z = pack2((R1).x, (R1).y); P_.w = pack2((R1).z, (R1).w); \
        *reinterpret_cast<uint4*>(&xstage[BUF][kfs][lps][0]) = P_; } while (0)

// chained XPROJ — used ONCE in the prologue only (not perf-critical)
#define XPROJ(SB, AB) do { \
        const short8 PA0 = *reinterpret_cast<const short8*>(&xstage[SB][0][lane][0]); \
        const short8 PA1 = *reinterpret_cast<const short8*>(&xstage[SB][1][lane][0]); \
        const short8 PA2 = *reinterpret_cast<const short8*>(&xstage[SB][2][lane][0]); \
        const short8 PA3 = *reinterpret_cast<const short8*>(&xstage[SB][3][lane][0]); \
        f32x4 ac0 = z4, ac1 = z4; \
        ac0 = __builtin_amdgcn_mfma_f32_16x16x32_bf16(PA0, WF[0][0], ac0, 0, 0, 0); \
        ac0 = __builtin_amdgcn_mfma_f32_16x16x32_bf16(PA1, WF[0][1], ac0, 0, 0, 0); \
        ac0 = __builtin_amdgcn_mfma_f32_16x16x32_bf16(PA2, WF[0][2], ac0, 0, 0, 0); \
        ac0 = __builtin_amdgcn_mfma_f32_16x16x32_bf16(PA3, WF[0][3], ac0, 0, 0, 0); \
        ac1 = __builtin_amdgcn_mfma_f32_16x16x32_bf16(PA0, WF[1][0], ac1, 0, 0, 0); \
        ac1 = __builtin_amdgcn_mfma_f32_16x16x32_bf16(PA1, WF[1][1], ac1, 0, 0, 0); \
        ac1 = __builtin_amdgcn_mfma_f32_16x16x32_bf16(PA2, WF[1][2], ac1, 0, 0, 0); \
        ac1 = __builtin_amdgcn_mfma_f32_16x16x32_bf16(PA3, WF[1][3], ac1, 0, 0, 0); \
        const int c_ = lane & 15, rb_ = (lane >> 4) * 4; \
        _Pragma("unroll") \
        for (int r = 0; r < 4; ++r) { \
            axbuf[AB][rb_ + r][jb + c_]      = ac0[r] + biasv[0]; \
            axbuf[AB][rb_ + r][jb + 16 + c_] = ac1[r] + biasv[1]; \
        } } while (0)

    // ---------------- prologue ----------------
    float4 nr0, nr1;
    if (!hw) {
        float4 p0 = *reinterpret_cast<const float4*>(&xb[t_s * II + i0]);
        float4 p1 = *reinterpret_cast<const float4*>(&xb[t_s * II + i0 + 4]);
        STAGE_X(1, p0, p1);
        nr0 = *reinterpret_cast<const float4*>(&xb[(GS + t_s) * II + i0]);
        nr1 = *reinterpret_cast<const float4*>(&xb[(GS + t_s) * II + i0 + 4]);
    }
    if (tid < HH) hA[0][tid] = 0;          // bf16 zero (permutation-invariant)
    __syncthreads();
    if (!hw) {
        XPROJ(1, 0);             // axbuf[0] (group 0)
        STAGE_X(0, nr0, nr1);    // xstage[0] <- x of group 1
    }
    __syncthreads();

    // h-wave persistent state
    const int c16 = lane & 15;
    float axn0 = 0.f, axn1 = 0.f;
    f32x4 d00 = z4, d10 = z4;      // persistent ax-seeded accumulators
    float* ob = out + (size_t)b * (TT * HH) + jb_h + lane;
    if (hw) {
        axn0 = axbuf[0][0][jb_h + c16];
        axn1 = axbuf[0][0][jb_h + 16 + c16];
    }

    // x-wave persistent pipeline registers
    short8 XA0 = {}, XA1 = {}, XA2 = {}, XA3 = {};
    f32x4 xp0 = z4, xp1 = z4, xp2 = z4, xp3 = z4;
    f32x4 yp0 = z4, yp1 = z4, yp2 = z4, yp3 = z4;

    // ---------------- main loop ----------------
    for (int g = 0; g < NG; ++g) {
#pragma unroll
        for (int w = 0; w < GS; ++w) {
            if (hw) {
                const int p  = w & 1;
                const int ko = (lane >> 4) * 8;
                // A = h broadcast into all 16 rows (permuted k-layout matches WH)
                const short8 A0 = *reinterpret_cast<const short8*>(&hA[p][ 0 + ko]);
                const short8 A1 = *reinterpret_cast<const short8*>(&hA[p][32 + ko]);
                const short8 A2 = *reinterpret_cast<const short8*>(&hA[p][64 + ko]);
                const short8 A3 = *reinterpret_cast<const short8*>(&hA[p][96 + ko]);
                // seed ax into C of the first acc of each n-tile (1 mov each;
                // stale [1..3] never read, bounded accumulation)
                d00[0] = axn0;
                d10[0] = axn1;
                f32x4 e01, e02, e03, e11, e12, e13;
                d00 = __builtin_amdgcn_mfma_f32_16x16x32_bf16(A0, WH[0][0], d00, 0, 0, 0);
                e01 = __builtin_amdgcn_mfma_f32_16x16x32_bf16(A1, WH[0][1], z4,  0, 0, 0);
                e02 = __builtin_amdgcn_mfma_f32_16x16x32_bf16(A2, WH[0][2], z4,  0, 0, 0);
                e03 = __builtin_amdgcn_mfma_f32_16x16x32_bf16(A3, WH[0][3], z4,  0, 0, 0);
                d10 = __builtin_amdgcn_mfma_f32_16x16x32_bf16(A0, WH[1][0], d10, 0, 0, 0);
                e11 = __builtin_amdgcn_mfma_f32_16x16x32_bf16(A1, WH[1][1], z4,  0, 0, 0);
                e12 = __builtin_amdgcn_mfma_f32_16x16x32_bf16(A2, WH[1][2], z4,  0, 0, 0);
                e13 = __builtin_amdgcn_mfma_f32_16x16x32_bf16(A3, WH[1][3], z4,  0, 0, 0);
                // prefetch next step's ax (hidden under MFMA completion)
                {
                    const int wn  = (w + 1) & (GS - 1);
                    const int gnb = (w == GS - 1) ? ((g + 1) & 1) : (g & 1);
                    axn0 = axbuf[gnb][wn][jb_h + c16];
                    axn1 = axbuf[gnb][wn][jb_h + 16 + c16];
                }
                // 2-level add tree (ax already inside d00/d10)
                const float s0 = (d00[0] + e01[0]) + (e02[0] + e03[0]);
                const float s1 = (d10[0] + e11[0]) + (e12[0] + e13[0]);
                const float hn0 = tanh_fast(s0);
                const float hn1 = tanh_fast(s1);
                if (lane < 16) {
                    // permuted layout: cols (jb_h+lane, jb_h+16+lane) are
                    // adjacent slots -> ONE packed dword write
                    *reinterpret_cast<unsigned int*>(&hA[p ^ 1][jb_h + 2 * lane])
                        = pack2(hn0, hn1);
                    ob[0]  = hn0;     // fire-and-forget; no vmcnt wait in loop
                    ob[16] = hn1;
                }
                ob += HH;
            } else {
                // ---- spread x-pipeline: <=1 MFMA per step, no w==0 spike ----
                if (w == 0 && g + 1 < NG) {
                    XA0 = *reinterpret_cast<const short8*>(&xstage[g & 1][0][lane][0]);
                    XA1 = *reinterpret_cast<const short8*>(&xstage[g & 1][1][lane][0]);
                    XA2 = *reinterpret_cast<const short8*>(&xstage[g & 1][2][lane][0]);
                    XA3 = *reinterpret_cast<const short8*>(&xstage[g & 1][3][lane][0]);
                }
                if (w == 1 && g + 2 < NG) {
                    const int tb = (g + 2) * GS;
                    nr0 = *reinterpret_cast<const float4*>(&xb[(size_t)(tb + t_s) * II + i0]);
                    nr1 = *reinterpret_cast<const float4*>(&xb[(size_t)(tb + t_s) * II + i0 + 4]);
                }
                if (g + 1 < NG) {
                    if (w == 1) xp0 = __builtin_amdgcn_mfma_f32_16x16x32_bf16(XA0, WF[0][0], bs0, 0, 0, 0);
                    if (w == 2) yp0 = __builtin_amdgcn_mfma_f32_16x16x32_bf16(XA0, WF[1][0], bs1, 0, 0, 0);
                    if (w == 3) xp1 = __builtin_amdgcn_mfma_f32_16x16x32_bf16(XA1, WF[0][1], z4, 0, 0, 0);
                    if (w == 4) yp1 = __builtin_amdgcn_mfma_f32_16x16x32_bf16(XA1, WF[1][1], z4, 0, 0, 0);
                    if (w == 5) xp2 = __builtin_amdgcn_mfma_f32_16x16x32_bf16(XA2, WF[0][2], z4, 0, 0, 0);
                    if (w == 6) yp2 = __builtin_amdgcn_mfma_f32_16x16x32_bf16(XA2, WF[1][2], z4, 0, 0, 0);
                    if (w == 7) xp3 = __builtin_amdgcn_mfma_f32_16x16x32_bf16(XA3, WF[0][3], z4, 0, 0, 0);
                    if (w == 8) yp3 = __builtin_amdgcn_mfma_f32_16x16x32_bf16(XA3, WF[1][3], z4, 0, 0, 0);
                    if (w == 9) {
                        const f32x4 t0 = (xp0 + xp1) + (xp2 + xp3);   // bias in xp0
                        const f32x4 t1 = (yp0 + yp1) + (yp2 + yp3);   // bias in yp0
                        const int c_ = lane & 15, rb_ = (lane >> 4) * 4;
#pragma unroll
                        for (int r = 0; r < 4; ++r) {
                            axbuf[(g + 1) & 1][rb_ + r][jb + c_]      = t0[r];
                            axbuf[(g + 1) & 1][rb_ + r][jb + 16 + c_] = t1[r];
                        }
                    }
                }
                if (w == 11 && g + 2 < NG) {
                    STAGE_X((g + 1) & 1, nr0, nr1);   // x of group g+2
                }
            }
            step_barrier();
        }
    }
#undef XPROJ
#undef STAGE_X
}

extern "C" void kernel_launch(void* const* d_in, const int* in_sizes, int n_in,
                              void* d_out, int out_size, void* d_ws, size_t ws_size,
                              hipStream_t stream) {
    const float* x    = (const float*)d_in[0];
    const float* w_ih = (const float*)d_in[1];
    const float* w_hh = (const float*)d_in[2];
    const float* b_ih = (const float*)d_in[3];
    const float* b_hh = (const float*)d_in[4];
    float* out = (float*)d_out;

    rnn_pipe<<<BB, 512, 0, stream>>>(x, w_ih, w_hh, b_ih, b_hh, out);
}

// Round 4
// 502.590 us; speedup vs baseline: 1.1073x; 1.0198x over previous
//
#include <hip/hip_runtime.h>

#define BB 256
#define TT 2048
#define II 128
#define HH 128
#define GS 16              // steps per group
#define NG (TT / GS)       // 128 groups

typedef __attribute__((ext_vector_type(8))) short short8;  // 8 bf16 (4 VGPR)
typedef __attribute__((ext_vector_type(4))) float f32x4;   // MFMA C/D

// Light per-step barrier: drain LDS ops then barrier in ONE asm block
// (vmcnt NOT drained — x-prefetch loads / out-stores fly across steps).
__device__ __forceinline__ void step_barrier() {
    asm volatile("s_waitcnt lgkmcnt(0)\n\ts_barrier" ::: "memory");
}

__device__ __forceinline__ float tanh_fast(float s) {
    // tanh(s) = 1 - 2/(e^{2s}+1); e^{2s} = 2^(s * 2/ln2), one v_exp_f32.
#if __has_builtin(__builtin_amdgcn_exp2f)
    const float e = __builtin_amdgcn_exp2f(s * 2.8853900817779268f);
#else
    const float e = exp2f(s * 2.8853900817779268f);
#endif
    return 1.0f - 2.0f * __builtin_amdgcn_rcpf(e + 1.0f);
}

// float -> bf16 round-to-nearest-even
__device__ __forceinline__ unsigned int f2bf(float f) {
    unsigned int u = __float_as_uint(f);
    u += 0x7FFF + ((u >> 16) & 1);
    return u >> 16;
}
__device__ __forceinline__ unsigned int pack2(float lo, float hi) {
    return f2bf(lo) | (f2bf(hi) << 16);
}

// R17: PARK the x-waves. R16 spread x-work across steps, but x-waves still
// added per-step barrier skew (XA ds_read lgkm drains, stores, loop VALU on
// the SIMD shared with an h-wave). Now ALL per-group x-work is concentrated
// in ONE window at w==14 (~400c < h-step ~600c, so x reaches b14 first);
// the other 15 barriers see x-waves already parked AT the barrier
// (suspended, zero issue interference, zero skew) -> effectively a 4-wave
// barrier for h-steps. Race-free via a DISTANCE-2 ax pipeline with 3
// buffers: window at group g projects ax for group g+2 into axbuf[(g+2)%3];
// h's w==15 prefetch of axbuf[(g+1)%3] reads data written a full group
// (>=2 barriers) earlier. xstage stays ping-pong (write (g+1)&1, read g&1,
// one group apart); global x loads run one window ahead (nr regs).
// h datapath is R16 verbatim: broadcast-A ds_reads, persistent ax-seeded
// d00/d10 (stale [1..3] unread), z4-fed e-accs, 2-level tree, tanh,
// permuted-hA single packed ds_write_b32, fire-and-forget out stores.
__launch_bounds__(512, 1)
__global__ void rnn_pipe(const float* __restrict__ x,
                         const float* __restrict__ w_ih,
                         const float* __restrict__ w_hh,
                         const float* __restrict__ b_ih,
                         const float* __restrict__ b_hh,
                         float* __restrict__ out) {
    const int b    = blockIdx.x;
    const int tid  = threadIdx.x;
    const int wave = tid >> 6;
    const int lane = tid & 63;
    const bool hw  = (wave < 4);

    __shared__ __align__(16) unsigned short hA[2][HH];           // bf16 h ping-pong (k-permuted)
    __shared__ __align__(16) float axbuf[3][GS][HH];             // 24 KB, distance-2 pipeline
    __shared__ __align__(16) unsigned short xstage[2][4][64][8]; // 8 KB bf16 A-frags

    const float* xb = x + (size_t)b * (TT * II);
    const f32x4 z4 = {0.f, 0.f, 0.f, 0.f};   // hoisted MFMA C zero

    // ---------------- h-wave setup: W_hh B-frags (bf16, k-permuted) ----------------
    const int jb_h = (wave & 3) * 32;    // h-wave owns cols [jb_h, jb_h+32)
    short8 WH[2][4];
    if (hw) {
#pragma unroll
        for (int nt = 0; nt < 2; ++nt) {
            const int jj = jb_h + nt * 16 + (lane & 15);
#pragma unroll
            for (int kf = 0; kf < 4; ++kf) {
                short8 s;
#pragma unroll
                for (int e = 0; e < 8; ++e) {
                    const int kp = kf * 32 + (lane >> 4) * 8 + e;  // A-slot index
                    const int mm = kp & 31;
                    // slot -> original k: 32a+2c -> 32a+c ; 32a+2c+1 -> 32a+16+c
                    const int ko = (kp & ~31) + (mm >> 1) + ((mm & 1) << 4);
                    s[e] = (short)f2bf(w_hh[(size_t)jj * HH + ko]);
                }
                WH[nt][kf] = s;
            }
        }
    }

    // ---------------- x-wave setup ----------------
    const int xwq = wave - 4;        // 0..3
    const int jb  = xwq * 32;        // owns j in [jb, jb+32): 2 N-tiles
    short8 WF[2][4];
    float biasv[2];
    f32x4 bs0 = z4, bs1 = z4;        // bias splats (MFMA C seeds)
    const int q   = tid - 256;       // 0..255 for x-threads
    const int t_s = q >> 4;          // 0..15
    const int m   = q & 15;
    const int i0  = m * 8;
    const int kfs = m >> 2;                  // k-frag of this chunk
    const int lps = (m & 3) * 16 + t_s;      // A-frag lane slot
    if (!hw) {
#pragma unroll
        for (int nt = 0; nt < 2; ++nt) {
            const int jj = jb + nt * 16 + (lane & 15);
            biasv[nt] = b_ih[jj] + b_hh[jj];
#pragma unroll
            for (int kf = 0; kf < 4; ++kf) {
                const float* wp = w_ih + (size_t)jj * II + kf * 32 + (lane >> 4) * 8;
                short8 s;
#pragma unroll
                for (int e = 0; e < 8; ++e) s[e] = (short)f2bf(wp[e]);
                WF[nt][kf] = s;
            }
        }
#pragma unroll
        for (int r = 0; r < 4; ++r) { bs0[r] = biasv[0]; bs1[r] = biasv[1]; }
    }

#define STAGE_X(BUF, R0, R1) do { \
        uint4 P_; P_.x = pack2((R0).x, (R0).y); P_.y = pack2((R0).z, (R0).w); \
        P_.z = pack2((R1).x, (R1).y); P_.w = pack2((R1).z, (R1).w); \
        *reinterpret_cast<uint4*>(&xstage[BUF][kfs][lps][0]) = P_; } while (0)

// chained XPROJ — used in the prologue only (not perf-critical)
#define XPROJ(SB, AB) do { \
        const short8 PA0 = *reinterpret_cast<const short8*>(&xstage[SB][0][lane][0]); \
        const short8 PA1 = *reinterpret_cast<const short8*>(&xstage[SB][1][lane][0]); \
        const short8 PA2 = *reinterpret_cast<const short8*>(&xstage[SB][2][lane][0]); \
        const short8 PA3 = *reinterpret_cast<const short8*>(&xstage[SB][3][lane][0]); \
        f32x4 ac0 = z4, ac1 = z4; \
        ac0 = __builtin_amdgcn_mfma_f32_16x16x32_bf16(PA0, WF[0][0], ac0, 0, 0, 0); \
        ac0 = __builtin_amdgcn_mfma_f32_16x16x32_bf16(PA1, WF[0][1], ac0, 0, 0, 0); \
        ac0 = __builtin_amdgcn_mfma_f32_16x16x32_bf16(PA2, WF[0][2], ac0, 0, 0, 0); \
        ac0 = __builtin_amdgcn_mfma_f32_16x16x32_bf16(PA3, WF[0][3], ac0, 0, 0, 0); \
        ac1 = __builtin_amdgcn_mfma_f32_16x16x32_bf16(PA0, WF[1][0], ac1, 0, 0, 0); \
        ac1 = __builtin_amdgcn_mfma_f32_16x16x32_bf16(PA1, WF[1][1], ac1, 0, 0, 0); \
        ac1 = __builtin_amdgcn_mfma_f32_16x16x32_bf16(PA2, WF[1][2], ac1, 0, 0, 0); \
        ac1 = __builtin_amdgcn_mfma_f32_16x16x32_bf16(PA3, WF[1][3], ac1, 0, 0, 0); \
        const int c_ = lane & 15, rb_ = (lane >> 4) * 4; \
        _Pragma("unroll") \
        for (int r = 0; r < 4; ++r) { \
            axbuf[AB][rb_ + r][jb + c_]      = ac0[r] + biasv[0]; \
            axbuf[AB][rb_ + r][jb + 16 + c_] = ac1[r] + biasv[1]; \
        } } while (0)

    // ---------------- prologue: prime axbuf[0],[1]; xstage[0]<-x(g2); nr<-x(g3) ----------------
    float4 nr0, nr1;
    if (!hw) {
        float4 p0 = *reinterpret_cast<const float4*>(&xb[t_s * II + i0]);
        float4 p1 = *reinterpret_cast<const float4*>(&xb[t_s * II + i0 + 4]);
        STAGE_X(0, p0, p1);                    // x of group 0
    }
    if (tid < HH) hA[0][tid] = 0;              // bf16 zero (permutation-invariant)
    __syncthreads();
    if (!hw) XPROJ(0, 0);                      // axbuf[0] <- ax(group 0)
    __syncthreads();
    if (!hw) {
        float4 p0 = *reinterpret_cast<const float4*>(&xb[(GS + t_s) * II + i0]);
        float4 p1 = *reinterpret_cast<const float4*>(&xb[(GS + t_s) * II + i0 + 4]);
        STAGE_X(0, p0, p1);                    // x of group 1 (reuse buf 0)
    }
    __syncthreads();
    if (!hw) XPROJ(0, 1);                      // axbuf[1] <- ax(group 1)
    __syncthreads();
    if (!hw) {
        float4 p0 = *reinterpret_cast<const float4*>(&xb[(2 * GS + t_s) * II + i0]);
        float4 p1 = *reinterpret_cast<const float4*>(&xb[(2 * GS + t_s) * II + i0 + 4]);
        STAGE_X(0, p0, p1);                    // xstage[0] <- x of group 2 (window g=0 reads it)
        nr0 = *reinterpret_cast<const float4*>(&xb[(size_t)(3 * GS + t_s) * II + i0]);
        nr1 = *reinterpret_cast<const float4*>(&xb[(size_t)(3 * GS + t_s) * II + i0 + 4]);
    }
    __syncthreads();

    // h-wave persistent state
    const int c16 = lane & 15;
    float axn0 = 0.f, axn1 = 0.f;
    f32x4 d00 = z4, d10 = z4;      // persistent ax-seeded accumulators
    float* ob = out + (size_t)b * (TT * HH) + jb_h + lane;
    if (hw) {
        axn0 = axbuf[0][0][jb_h + c16];
        axn1 = axbuf[0][0][jb_h + 16 + c16];
    }

    // ---------------- main loop ----------------
    for (int g = 0; g < NG; ++g) {
        const int g3  = g % 3;             // h read buffer
        const int g3n = (g + 1) % 3;       // h w==15 prefetch buffer
        const int g3x = (g + 2) % 3;       // x window write buffer
#pragma unroll
        for (int w = 0; w < GS; ++w) {
            if (hw) {
                const int p  = w & 1;
                const int ko = (lane >> 4) * 8;
                // A = h broadcast into all 16 rows (permuted k-layout matches WH)
                const short8 A0 = *reinterpret_cast<const short8*>(&hA[p][ 0 + ko]);
                const short8 A1 = *reinterpret_cast<const short8*>(&hA[p][32 + ko]);
                const short8 A2 = *reinterpret_cast<const short8*>(&hA[p][64 + ko]);
                const short8 A3 = *reinterpret_cast<const short8*>(&hA[p][96 + ko]);
                // seed ax into C of the first acc of each n-tile (1 mov each;
                // stale [1..3] never read, bounded accumulation)
                d00[0] = axn0;
                d10[0] = axn1;
                f32x4 e01, e02, e03, e11, e12, e13;
                d00 = __builtin_amdgcn_mfma_f32_16x16x32_bf16(A0, WH[0][0], d00, 0, 0, 0);
                e01 = __builtin_amdgcn_mfma_f32_16x16x32_bf16(A1, WH[0][1], z4,  0, 0, 0);
                e02 = __builtin_amdgcn_mfma_f32_16x16x32_bf16(A2, WH[0][2], z4,  0, 0, 0);
                e03 = __builtin_amdgcn_mfma_f32_16x16x32_bf16(A3, WH[0][3], z4,  0, 0, 0);
                d10 = __builtin_amdgcn_mfma_f32_16x16x32_bf16(A0, WH[1][0], d10, 0, 0, 0);
                e11 = __builtin_amdgcn_mfma_f32_16x16x32_bf16(A1, WH[1][1], z4,  0, 0, 0);
                e12 = __builtin_amdgcn_mfma_f32_16x16x32_bf16(A2, WH[1][2], z4,  0, 0, 0);
                e13 = __builtin_amdgcn_mfma_f32_16x16x32_bf16(A3, WH[1][3], z4,  0, 0, 0);
                // prefetch next step's ax (hidden under MFMA completion).
                // w==15 reads next group's buffer — written a FULL group ago
                // (distance-2 pipeline), so no race with this group's window.
                {
                    const int wn  = (w + 1) & (GS - 1);
                    const int gnb = (w == GS - 1) ? g3n : g3;
                    axn0 = axbuf[gnb][wn][jb_h + c16];
                    axn1 = axbuf[gnb][wn][jb_h + 16 + c16];
                }
                // 2-level add tree (ax already inside d00/d10)
                const float s0 = (d00[0] + e01[0]) + (e02[0] + e03[0]);
                const float s1 = (d10[0] + e11[0]) + (e12[0] + e13[0]);
                const float hn0 = tanh_fast(s0);
                const float hn1 = tanh_fast(s1);
                if (lane < 16) {
                    // permuted layout: cols (jb_h+lane, jb_h+16+lane) are
                    // adjacent slots -> ONE packed dword write
                    *reinterpret_cast<unsigned int*>(&hA[p ^ 1][jb_h + 2 * lane])
                        = pack2(hn0, hn1);
                    ob[0]  = hn0;     // fire-and-forget; no vmcnt wait in loop
                    ob[16] = hn1;
                }
                ob += HH;
            } else if (w == 14) {
                // ---- the ENTIRE per-group x pipeline, one window ----
                if (g + 2 < NG) {
                    // project ax for group g+2 from xstage[g&1] (staged at window g-1)
                    const short8 XA0 = *reinterpret_cast<const short8*>(&xstage[g & 1][0][lane][0]);
                    const short8 XA1 = *reinterpret_cast<const short8*>(&xstage[g & 1][1][lane][0]);
                    const short8 XA2 = *reinterpret_cast<const short8*>(&xstage[g & 1][2][lane][0]);
                    const short8 XA3 = *reinterpret_cast<const short8*>(&xstage[g & 1][3][lane][0]);
                    // 8 independent MFMAs (bias-seeded first pair) + 2-level tree
                    f32x4 xp0, xp1, xp2, xp3, yp0, yp1, yp2, yp3;
                    xp0 = __builtin_amdgcn_mfma_f32_16x16x32_bf16(XA0, WF[0][0], bs0, 0, 0, 0);
                    yp0 = __builtin_amdgcn_mfma_f32_16x16x32_bf16(XA0, WF[1][0], bs1, 0, 0, 0);
                    xp1 = __builtin_amdgcn_mfma_f32_16x16x32_bf16(XA1, WF[0][1], z4, 0, 0, 0);
                    yp1 = __builtin_amdgcn_mfma_f32_16x16x32_bf16(XA1, WF[1][1], z4, 0, 0, 0);
                    xp2 = __builtin_amdgcn_mfma_f32_16x16x32_bf16(XA2, WF[0][2], z4, 0, 0, 0);
                    yp2 = __builtin_amdgcn_mfma_f32_16x16x32_bf16(XA2, WF[1][2], z4, 0, 0, 0);
                    xp3 = __builtin_amdgcn_mfma_f32_16x16x32_bf16(XA3, WF[0][3], z4, 0, 0, 0);
                    yp3 = __builtin_amdgcn_mfma_f32_16x16x32_bf16(XA3, WF[1][3], z4, 0, 0, 0);
                    const f32x4 t0 = (xp0 + xp1) + (xp2 + xp3);
                    const f32x4 t1 = (yp0 + yp1) + (yp2 + yp3);
                    const int c_ = lane & 15, rb_ = (lane >> 4) * 4;
#pragma unroll
                    for (int r = 0; r < 4; ++r) {
                        axbuf[g3x][rb_ + r][jb + c_]      = t0[r];
                        axbuf[g3x][rb_ + r][jb + 16 + c_] = t1[r];
                    }
                }
                if (g + 3 < NG) {
                    STAGE_X((g + 1) & 1, nr0, nr1);   // x of group g+3 (loaded last window)
                }
                if (g + 4 < NG) {
                    const int tb = (g + 4) * GS;      // load x of group g+4 for next window
                    nr0 = *reinterpret_cast<const float4*>(&xb[(size_t)(tb + t_s) * II + i0]);
                    nr1 = *reinterpret_cast<const float4*>(&xb[(size_t)(tb + t_s) * II + i0 + 4]);
                }
            }
            step_barrier();
        }
    }
#undef XPROJ
#undef STAGE_X
}

extern "C" void kernel_launch(void* const* d_in, const int* in_sizes, int n_in,
                              void* d_out, int out_size, void* d_ws, size_t ws_size,
                              hipStream_t stream) {
    const float* x    = (const float*)d_in[0];
    const float* w_ih = (const float*)d_in[1];
    const float* w_hh = (const float*)d_in[2];
    const float* b_ih = (const float*)d_in[3];
    const float* b_hh = (const float*)d_in[4];
    float* out = (float*)d_out;

    rnn_pipe<<<BB, 512, 0, stream>>>(x, w_ih, w_hh, b_ih, b_hh, out);
}

// Round 5
// 465.740 us; speedup vs baseline: 1.1949x; 1.0791x over previous
//
#include <hip/hip_runtime.h>

#define BB 256
#define TT 2048
#define II 128
#define HH 128
#define GS 16              // steps per group
#define NG (TT / GS)       // 128 groups

typedef __attribute__((ext_vector_type(8))) short short8;  // 8 bf16 (4 VGPR)
typedef __attribute__((ext_vector_type(4))) float f32x4;   // MFMA C/D

// Light per-step barrier: drain LDS ops then barrier in ONE asm block
// (vmcnt NOT drained — x-prefetch loads / out-stores fly across steps).
__device__ __forceinline__ void step_barrier() {
    asm volatile("s_waitcnt lgkmcnt(0)\n\ts_barrier" ::: "memory");
}

__device__ __forceinline__ float tanh_fast(float s) {
    // tanh(s) = 1 - 2/(e^{2s}+1); e^{2s} = 2^(s * 2/ln2), one v_exp_f32.
#if __has_builtin(__builtin_amdgcn_exp2f)
    const float e = __builtin_amdgcn_exp2f(s * 2.8853900817779268f);
#else
    const float e = exp2f(s * 2.8853900817779268f);
#endif
    return 1.0f - 2.0f * __builtin_amdgcn_rcpf(e + 1.0f);
}

// float -> bf16 round-to-nearest-even (scalar/setup paths)
__device__ __forceinline__ unsigned int f2bf(float f) {
    unsigned int u = __float_as_uint(f);
    u += 0x7FFF + ((u >> 16) & 1);
    return u >> 16;
}
// hot-path pack: ONE v_cvt_pk_bf16_f32 (lo = a, hi = b)
__device__ __forceinline__ unsigned int cvtpk(float a, float b) {
    unsigned int r;
    asm("v_cvt_pk_bf16_f32 %0, %1, %2" : "=v"(r) : "v"(a), "v"(b));
    return r;
}

// R18: strip the h-wave tail. R17 measured ~590 c/step (floor ~440):
//  (1) out[] stores MOVED TO THE PARKED X-WAVES: after each barrier an
//      x-wave reads the PREVIOUS parity of hA (race-free: h writes the
//      other parity; read drains at x's own barrier), upconverts
//      bf16->f32, stores. Removes exec-mask + 2 global stores + ob
//      bookkeeping from the h critical path. out is now the bf16-rounded
//      state (== what the recurrence consumes): +<=0.001 absmax.
//      Final timestep flushed in an epilogue from hA[0].
//  (2) pack2 (≈9 VALU ops) -> ONE v_cvt_pk_bf16_f32.
//  (3) s_setprio(1) on h-waves: protects the serial chain's MFMAs from
//      the x-wave's 8 window-MFMAs sharing the SIMD at w==14.
// Everything else is R17 verbatim: parked x-waves with the single w==14
// window, distance-2 ax pipeline (3 buffers), persistent ax-seeded
// d00/d10, z4-fed e-accs, broadcast-A ds_reads, permuted hA layout.
__launch_bounds__(512, 1)
__global__ void rnn_pipe(const float* __restrict__ x,
                         const float* __restrict__ w_ih,
                         const float* __restrict__ w_hh,
                         const float* __restrict__ b_ih,
                         const float* __restrict__ b_hh,
                         float* __restrict__ out) {
    const int b    = blockIdx.x;
    const int tid  = threadIdx.x;
    const int wave = tid >> 6;
    const int lane = tid & 63;
    const bool hw  = (wave < 4);

    __shared__ __align__(16) unsigned short hA[2][HH];           // bf16 h ping-pong (k-permuted)
    __shared__ __align__(16) float axbuf[3][GS][HH];             // 24 KB, distance-2 pipeline
    __shared__ __align__(16) unsigned short xstage[2][4][64][8]; // 8 KB bf16 A-frags

    const float* xb = x + (size_t)b * (TT * II);
    const f32x4 z4 = {0.f, 0.f, 0.f, 0.f};   // hoisted MFMA C zero

    // ---------------- h-wave setup: W_hh B-frags (bf16, k-permuted) ----------------
    const int jb_h = (wave & 3) * 32;    // h-wave owns cols [jb_h, jb_h+32)
    short8 WH[2][4];
    if (hw) {
#pragma unroll
        for (int nt = 0; nt < 2; ++nt) {
            const int jj = jb_h + nt * 16 + (lane & 15);
#pragma unroll
            for (int kf = 0; kf < 4; ++kf) {
                short8 s;
#pragma unroll
                for (int e = 0; e < 8; ++e) {
                    const int kp = kf * 32 + (lane >> 4) * 8 + e;  // A-slot index
                    const int mm = kp & 31;
                    // slot -> original k: 32a+2c -> 32a+c ; 32a+2c+1 -> 32a+16+c
                    const int ko = (kp & ~31) + (mm >> 1) + ((mm & 1) << 4);
                    s[e] = (short)f2bf(w_hh[(size_t)jj * HH + ko]);
                }
                WH[nt][kf] = s;
            }
        }
    }

    // ---------------- x-wave setup ----------------
    const int xwq = wave - 4;        // 0..3
    const int jb  = xwq * 32;        // owns j in [jb, jb+32): 2 N-tiles
    short8 WF[2][4];
    float biasv[2];
    f32x4 bs0 = z4, bs1 = z4;        // bias splats (MFMA C seeds)
    const int q   = tid - 256;       // 0..255 for x-threads
    const int t_s = q >> 4;          // 0..15
    const int m   = q & 15;
    const int i0  = m * 8;
    const int kfs = m >> 2;                  // k-frag of this chunk
    const int lps = (m & 3) * 16 + t_s;      // A-frag lane slot
    const int c16 = lane & 15;
    if (!hw) {
#pragma unroll
        for (int nt = 0; nt < 2; ++nt) {
            const int jj = jb + nt * 16 + (lane & 15);
            biasv[nt] = b_ih[jj] + b_hh[jj];
#pragma unroll
            for (int kf = 0; kf < 4; ++kf) {
                const float* wp = w_ih + (size_t)jj * II + kf * 32 + (lane >> 4) * 8;
                short8 s;
#pragma unroll
                for (int e = 0; e < 8; ++e) s[e] = (short)f2bf(wp[e]);
                WF[nt][kf] = s;
            }
        }
#pragma unroll
        for (int r = 0; r < 4; ++r) { bs0[r] = biasv[0]; bs1[r] = biasv[1]; }
    }

#define STAGE_X(BUF, R0, R1) do { \
        uint4 P_; \
        P_.x = cvtpk((R0).x, (R0).y); P_.y = cvtpk((R0).z, (R0).w); \
        P_.z = cvtpk((R1).x, (R1).y); P_.w = cvtpk((R1).z, (R1).w); \
        *reinterpret_cast<uint4*>(&xstage[BUF][kfs][lps][0]) = P_; } while (0)

// chained XPROJ — used in the prologue only (not perf-critical)
#define XPROJ(SB, AB) do { \
        const short8 PA0 = *reinterpret_cast<const short8*>(&xstage[SB][0][lane][0]); \
        const short8 PA1 = *reinterpret_cast<const short8*>(&xstage[SB][1][lane][0]); \
        const short8 PA2 = *reinterpret_cast<const short8*>(&xstage[SB][2][lane][0]); \
        const short8 PA3 = *reinterpret_cast<const short8*>(&xstage[SB][3][lane][0]); \
        f32x4 ac0 = z4, ac1 = z4; \
        ac0 = __builtin_amdgcn_mfma_f32_16x16x32_bf16(PA0, WF[0][0], ac0, 0, 0, 0); \
        ac0 = __builtin_amdgcn_mfma_f32_16x16x32_bf16(PA1, WF[0][1], ac0, 0, 0, 0); \
        ac0 = __builtin_amdgcn_mfma_f32_16x16x32_bf16(PA2, WF[0][2], ac0, 0, 0, 0); \
        ac0 = __builtin_amdgcn_mfma_f32_16x16x32_bf16(PA3, WF[0][3], ac0, 0, 0, 0); \
        ac1 = __builtin_amdgcn_mfma_f32_16x16x32_bf16(PA0, WF[1][0], ac1, 0, 0, 0); \
        ac1 = __builtin_amdgcn_mfma_f32_16x16x32_bf16(PA1, WF[1][1], ac1, 0, 0, 0); \
        ac1 = __builtin_amdgcn_mfma_f32_16x16x32_bf16(PA2, WF[1][2], ac1, 0, 0, 0); \
        ac1 = __builtin_amdgcn_mfma_f32_16x16x32_bf16(PA3, WF[1][3], ac1, 0, 0, 0); \
        const int c_ = lane & 15, rb_ = (lane >> 4) * 4; \
        _Pragma("unroll") \
        for (int r = 0; r < 4; ++r) { \
            axbuf[AB][rb_ + r][jb + c_]      = ac0[r] + biasv[0]; \
            axbuf[AB][rb_ + r][jb + 16 + c_] = ac1[r] + biasv[1]; \
        } } while (0)

    // ---------------- prologue: prime axbuf[0],[1]; xstage[0]<-x(g2); nr<-x(g3) ----------------
    float4 nr0, nr1;
    if (!hw) {
        float4 p0 = *reinterpret_cast<const float4*>(&xb[t_s * II + i0]);
        float4 p1 = *reinterpret_cast<const float4*>(&xb[t_s * II + i0 + 4]);
        STAGE_X(0, p0, p1);                    // x of group 0
    }
    if (tid < HH) hA[0][tid] = 0;              // bf16 zero (permutation-invariant)
    __syncthreads();
    if (!hw) XPROJ(0, 0);                      // axbuf[0] <- ax(group 0)
    __syncthreads();
    if (!hw) {
        float4 p0 = *reinterpret_cast<const float4*>(&xb[(GS + t_s) * II + i0]);
        float4 p1 = *reinterpret_cast<const float4*>(&xb[(GS + t_s) * II + i0 + 4]);
        STAGE_X(0, p0, p1);                    // x of group 1 (reuse buf 0)
    }
    __syncthreads();
    if (!hw) XPROJ(0, 1);                      // axbuf[1] <- ax(group 1)
    __syncthreads();
    if (!hw) {
        float4 p0 = *reinterpret_cast<const float4*>(&xb[(2 * GS + t_s) * II + i0]);
        float4 p1 = *reinterpret_cast<const float4*>(&xb[(2 * GS + t_s) * II + i0 + 4]);
        STAGE_X(0, p0, p1);                    // xstage[0] <- x of group 2 (window g=0 reads it)
        nr0 = *reinterpret_cast<const float4*>(&xb[(size_t)(3 * GS + t_s) * II + i0]);
        nr1 = *reinterpret_cast<const float4*>(&xb[(size_t)(3 * GS + t_s) * II + i0 + 4]);
    }
    __syncthreads();

    // h-wave persistent state
    float axn0 = 0.f, axn1 = 0.f;
    f32x4 d00 = z4, d10 = z4;      // persistent ax-seeded accumulators
    if (hw) {
        axn0 = axbuf[0][0][jb_h + c16];
        axn1 = axbuf[0][0][jb_h + 16 + c16];
        __builtin_amdgcn_s_setprio(1);    // protect the serial chain's MFMAs
    }

    // x-wave out-store pointer: lane c<16 -> col jb+c; lane 16+c -> col jb+16+c
    float* xout = nullptr;
    if (!hw && lane < 32) {
        xout = out + (size_t)b * (TT * HH) + jb + c16 + ((lane & 16) ? 16 : 0);
    }

    // ---------------- main loop ----------------
    for (int g = 0; g < NG; ++g) {
        const int g3  = g % 3;             // h read buffer
        const int g3n = (g + 1) % 3;       // h w==15 prefetch buffer
        const int g3x = (g + 2) % 3;       // x window write buffer
#pragma unroll
        for (int w = 0; w < GS; ++w) {
            if (hw) {
                const int p  = w & 1;
                const int ko = (lane >> 4) * 8;
                // A = h broadcast into all 16 rows (permuted k-layout matches WH)
                const short8 A0 = *reinterpret_cast<const short8*>(&hA[p][ 0 + ko]);
                const short8 A1 = *reinterpret_cast<const short8*>(&hA[p][32 + ko]);
                const short8 A2 = *reinterpret_cast<const short8*>(&hA[p][64 + ko]);
                const short8 A3 = *reinterpret_cast<const short8*>(&hA[p][96 + ko]);
                // seed ax into C of the first acc of each n-tile (1 mov each;
                // stale [1..3] never read, bounded accumulation)
                d00[0] = axn0;
                d10[0] = axn1;
                f32x4 e01, e02, e03, e11, e12, e13;
                d00 = __builtin_amdgcn_mfma_f32_16x16x32_bf16(A0, WH[0][0], d00, 0, 0, 0);
                e01 = __builtin_amdgcn_mfma_f32_16x16x32_bf16(A1, WH[0][1], z4,  0, 0, 0);
                e02 = __builtin_amdgcn_mfma_f32_16x16x32_bf16(A2, WH[0][2], z4,  0, 0, 0);
                e03 = __builtin_amdgcn_mfma_f32_16x16x32_bf16(A3, WH[0][3], z4,  0, 0, 0);
                d10 = __builtin_amdgcn_mfma_f32_16x16x32_bf16(A0, WH[1][0], d10, 0, 0, 0);
                e11 = __builtin_amdgcn_mfma_f32_16x16x32_bf16(A1, WH[1][1], z4,  0, 0, 0);
                e12 = __builtin_amdgcn_mfma_f32_16x16x32_bf16(A2, WH[1][2], z4,  0, 0, 0);
                e13 = __builtin_amdgcn_mfma_f32_16x16x32_bf16(A3, WH[1][3], z4,  0, 0, 0);
                // prefetch next step's ax (hidden under MFMA completion).
                // w==15 reads next group's buffer — written a FULL group ago
                // (distance-2 pipeline), so no race with this group's window.
                {
                    const int wn  = (w + 1) & (GS - 1);
                    const int gnb = (w == GS - 1) ? g3n : g3;
                    axn0 = axbuf[gnb][wn][jb_h + c16];
                    axn1 = axbuf[gnb][wn][jb_h + 16 + c16];
                }
                // 2-level add tree (ax already inside d00/d10)
                const float s0 = (d00[0] + e01[0]) + (e02[0] + e03[0]);
                const float s1 = (d10[0] + e11[0]) + (e12[0] + e13[0]);
                const float hn0 = tanh_fast(s0);
                const float hn1 = tanh_fast(s1);
                const unsigned int hpk = cvtpk(hn0, hn1);
                if (lane < 16) {
                    // permuted layout: cols (jb_h+lane, jb_h+16+lane) are
                    // adjacent slots -> ONE packed dword write
                    *reinterpret_cast<unsigned int*>(&hA[p ^ 1][jb_h + 2 * lane]) = hpk;
                }
            } else {
                // ---- park-and-store: stream out[T-1] from hA while h computes T ----
                const int T = (g << 4) + w;
                if (T != 0 && lane < 32) {
                    const unsigned int rd = *reinterpret_cast<const unsigned int*>(
                        &hA[w & 1][jb + 2 * c16]);
                    const unsigned int v = (lane & 16) ? (rd & 0xffff0000u) : (rd << 16);
                    xout[(size_t)(T - 1) * HH] = __uint_as_float(v);
                }
                if (w == 14) {
                    // ---- the ENTIRE per-group x pipeline, one window ----
                    if (g + 2 < NG) {
                        // project ax for group g+2 from xstage[g&1] (staged at window g-1)
                        const short8 XA0 = *reinterpret_cast<const short8*>(&xstage[g & 1][0][lane][0]);
                        const short8 XA1 = *reinterpret_cast<const short8*>(&xstage[g & 1][1][lane][0]);
                        const short8 XA2 = *reinterpret_cast<const short8*>(&xstage[g & 1][2][lane][0]);
                        const short8 XA3 = *reinterpret_cast<const short8*>(&xstage[g & 1][3][lane][0]);
                        // 8 independent MFMAs (bias-seeded first pair) + 2-level tree
                        f32x4 xp0, xp1, xp2, xp3, yp0, yp1, yp2, yp3;
                        xp0 = __builtin_amdgcn_mfma_f32_16x16x32_bf16(XA0, WF[0][0], bs0, 0, 0, 0);
                        yp0 = __builtin_amdgcn_mfma_f32_16x16x32_bf16(XA0, WF[1][0], bs1, 0, 0, 0);
                        xp1 = __builtin_amdgcn_mfma_f32_16x16x32_bf16(XA1, WF[0][1], z4, 0, 0, 0);
                        yp1 = __builtin_amdgcn_mfma_f32_16x16x32_bf16(XA1, WF[1][1], z4, 0, 0, 0);
                        xp2 = __builtin_amdgcn_mfma_f32_16x16x32_bf16(XA2, WF[0][2], z4, 0, 0, 0);
                        yp2 = __builtin_amdgcn_mfma_f32_16x16x32_bf16(XA2, WF[1][2], z4, 0, 0, 0);
                        xp3 = __builtin_amdgcn_mfma_f32_16x16x32_bf16(XA3, WF[0][3], z4, 0, 0, 0);
                        yp3 = __builtin_amdgcn_mfma_f32_16x16x32_bf16(XA3, WF[1][3], z4, 0, 0, 0);
                        const f32x4 t0 = (xp0 + xp1) + (xp2 + xp3);
                        const f32x4 t1 = (yp0 + yp1) + (yp2 + yp3);
                        const int c_ = lane & 15, rb_ = (lane >> 4) * 4;
#pragma unroll
                        for (int r = 0; r < 4; ++r) {
                            axbuf[g3x][rb_ + r][jb + c_]      = t0[r];
                            axbuf[g3x][rb_ + r][jb + 16 + c_] = t1[r];
                        }
                    }
                    if (g + 3 < NG) {
                        STAGE_X((g + 1) & 1, nr0, nr1);   // x of group g+3 (loaded last window)
                    }
                    if (g + 4 < NG) {
                        const int tb = (g + 4) * GS;      // load x of group g+4 for next window
                        nr0 = *reinterpret_cast<const float4*>(&xb[(size_t)(tb + t_s) * II + i0]);
                        nr1 = *reinterpret_cast<const float4*>(&xb[(size_t)(tb + t_s) * II + i0 + 4]);
                    }
                }
            }
            step_barrier();
        }
    }

    // ---------------- epilogue: flush out[TT-1] (in hA[0] after last step) ----------------
    if (!hw && lane < 32) {
        const unsigned int rd = *reinterpret_cast<const unsigned int*>(
            &hA[0][jb + 2 * c16]);
        const unsigned int v = (lane & 16) ? (rd & 0xffff0000u) : (rd << 16);
        xout[(size_t)(TT - 1) * HH] = __uint_as_float(v);
    }
#undef XPROJ
#undef STAGE_X
}

extern "C" void kernel_launch(void* const* d_in, const int* in_sizes, int n_in,
                              void* d_out, int out_size, void* d_ws, size_t ws_size,
                              hipStream_t stream) {
    const float* x    = (const float*)d_in[0];
    const float* w_ih = (const float*)d_in[1];
    const float* w_hh = (const float*)d_in[2];
    const float* b_ih = (const float*)d_in[3];
    const float* b_hh = (const float*)d_in[4];
    float* out = (float*)d_out;

    rnn_pipe<<<BB, 512, 0, stream>>>(x, w_ih, w_hh, b_ih, b_hh, out);
}